// Round 10
// baseline (50.605 us; speedup 1.0000x reference)
//
#include <hip/hip_runtime.h>
#include <stdint.h>

#define D_DIM 256
#define K_CTR 1024
#define B_ROWS 16384
#define BM 32
#define NBLK (B_ROWS / BM)   // 512 = exactly 2 blocks/CU * 256 CUs (all resident -> spin is safe)

typedef float f32x4 __attribute__((ext_vector_type(4)));
typedef long long i64x2 __attribute__((ext_vector_type(2)));

// Pack 4 f32 -> 4 fp8 e4m3 bytes (OCP, HW cvt).
static __device__ __forceinline__ unsigned cvt4_fp8(const float4 v) {
    int r = __builtin_amdgcn_cvt_pk_fp8_f32(v.x, v.y, 0, false);   // bytes 0-1
    r = __builtin_amdgcn_cvt_pk_fp8_f32(v.z, v.w, r, true);        // bytes 2-3
    return (unsigned)r;
}

// Fused: each block (a) converts 2 center rows to fp8 fragment-major cbf + csq,
// (b) stages its 32-row x strip, (c) release-add / RELAXED-spin / single-acquire
// on a device counter (no per-iteration buffer_inv storm -- R8's mistake),
// (d) 4-quarter MFMA + exp + LDS-staged single-segment stores (R7 machinery,
// no B prefetch: saves 32 VGPRs, prefetch was worth ~0.4us in R7).
//
// cbf layout: value c[col][d] (kk=d>>5, p=kk>>1, e=kk&1, hk=(d>>3)&3, j=d&7) at
// byte (col>>4)*4096 + p*1024 + (hk*16+(col&15))*16 + e*8 + j
// -> wave B-load (lane l) at p*1024 + l*16 is one contiguous 1KB dwordx4.
__global__ __launch_bounds__(512, 4) void rbf_fused(
        const float* __restrict__ x, const float* __restrict__ centers,
        unsigned char* __restrict__ cbf, float* __restrict__ csq,
        const float* __restrict__ betas, float* __restrict__ out,
        unsigned* __restrict__ counter) {
    __shared__ __align__(16) unsigned char As[BM * D_DIM];   // 8 KB fp8, swizzled
    __shared__ __align__(16) float obuf[2][BM * 256];        // 2 x 32 KB
    __shared__ float xs_lds[BM];

    const int tid = threadIdx.x;
    const int w = tid >> 6;
    const int l = tid & 63;
    // XCD-chunked bijective swizzle (512 = 8*64)
    const int strip = (blockIdx.x & 7) * 64 + (blockIdx.x >> 3);
    const int row0 = strip * BM;

    // ---- (a) fused prep slice: 2 center rows per block (threads 0..127) ----
    if (tid < 128) {
        const int c0 = blockIdx.x * 2 + w;   // w in {0,1}
        const float4 v = *reinterpret_cast<const float4*>(centers + c0 * D_DIM + l * 4);
        float s = v.x * v.x + v.y * v.y + v.z * v.z + v.w * v.w;
        const unsigned u = cvt4_fp8(v);
        const unsigned off = (unsigned)((c0 >> 4) * 4096 + (l >> 4) * 1024
                           + (((l >> 1) & 3) * 16 + (c0 & 15)) * 16
                           + ((l >> 3) & 1) * 8 + (l & 1) * 4);
        *reinterpret_cast<unsigned*>(cbf + off) = u;
        #pragma unroll
        for (int off2 = 1; off2 < 64; off2 <<= 1) s += __shfl_xor(s, off2);
        if (l == 0) csq[c0] = s;
    }

    // ---- (b) stage A strip as fp8 (swizzled) + x_sq ----
    #pragma unroll
    for (int i = 0; i < 4; ++i) {
        const int r = i * 8 + w;
        const float4 v = *reinterpret_cast<const float4*>(x + (size_t)(row0 + r) * D_DIM + l * 4);
        float s = v.x * v.x + v.y * v.y + v.z * v.z + v.w * v.w;
        const unsigned u = cvt4_fp8(v);
        const unsigned pos = (unsigned)((l >> 4) * 64 + ((l >> 1) & 3) * 16
                           + ((l >> 3) & 1) * 8 + (l & 1) * 4);
        *reinterpret_cast<unsigned*>(As + r * 256 + (pos ^ ((unsigned)(r & 7) << 4))) = u;
        #pragma unroll
        for (int off = 1; off < 64; off <<= 1) s += __shfl_xor(s, off);
        if (l == 0) xs_lds[r] = s;
    }
    __syncthreads();   // all waves' cbf/csq stores drained to L2; As ready

    // ---- (c) arrive + wait. RELEASE publishes this block's ~1KB of dirty prep
    //      lines (wbl2). Spin uses RELAXED loads (coherent point, NO cache
    //      invalidation). ONE acquire after exit invalidates stale L1/L2 once.
    if (tid == 0) {
        __hip_atomic_fetch_add(counter, 1u, __ATOMIC_RELEASE, __HIP_MEMORY_SCOPE_AGENT);
        while (__hip_atomic_load(counter, __ATOMIC_RELAXED, __HIP_MEMORY_SCOPE_AGENT) < NBLK)
            __builtin_amdgcn_s_sleep(8);
        (void)__hip_atomic_load(counter, __ATOMIC_ACQUIRE, __HIP_MEMORY_SCOPE_AGENT);
    }
    __syncthreads();

    const int hk = l >> 4;
    const int lr = l & 15;
    const unsigned char* bwave = cbf + l * 16;

    // ---- Hoist A frags once: 8 ds_read_b128 ----
    i64x2 a[2][4];
    #pragma unroll
    for (int m = 0; m < 2; ++m) {
        const int r = m * 16 + lr;
        #pragma unroll
        for (int p = 0; p < 4; ++p)
            a[m][p] = *reinterpret_cast<const i64x2*>(
                As + r * 256 + ((unsigned)(p * 64 + hk * 16) ^ ((unsigned)(lr & 7) << 4)));
    }
    const float xs0 = xs_lds[lr];
    const float xs1 = xs_lds[16 + lr];
    const float LOG2E = 1.4426950408889634f;

    #pragma unroll
    for (int ct = 0; ct < 4; ++ct) {
        const int colq = ct * 256;

        // ---- B for this quarter: 8 x 1KB coalesced dwordx4 (single buffer) ----
        i64x2 b[2][4];
        {
            const unsigned char* bbase = bwave + ((colq + w * 32) >> 4) * 4096;
            #pragma unroll
            for (int p = 0; p < 4; ++p)
                #pragma unroll
                for (int n = 0; n < 2; ++n)
                    b[n][p] = *reinterpret_cast<const i64x2*>(bbase + n * 4096 + p * 1024);
        }

        // ---- 32 MFMAs, 4 independent acc chains ----
        f32x4 acc[2][2] = {};
        #pragma unroll
        for (int p = 0; p < 4; ++p)
            #pragma unroll
            for (int n = 0; n < 2; ++n)
                #pragma unroll
                for (int m = 0; m < 2; ++m) {
                    acc[m][n] = __builtin_amdgcn_mfma_f32_16x16x32_fp8_fp8(b[n][p][0], a[m][p][0], acc[m][n], 0, 0, 0);
                    acc[m][n] = __builtin_amdgcn_mfma_f32_16x16x32_fp8_fp8(b[n][p][1], a[m][p][1], acc[m][n], 0, 0, 0);
                }

        // ---- Epilogue: exp2(fma(2*bt*log2e, acc, -bt*log2e*(xs+cs))) -> obuf ----
        float* ob = obuf[ct & 1];
        #pragma unroll
        for (int n = 0; n < 2; ++n) {
            const int cl = w * 32 + n * 16 + hk * 4;
            const f32x4 cs = *reinterpret_cast<const f32x4*>(csq + colq + cl);
            const f32x4 bt = *reinterpret_cast<const f32x4*>(betas + colq + cl);
            f32x4 btl2, coef2, base;
            #pragma unroll
            for (int j = 0; j < 4; ++j) {
                btl2[j] = bt[j] * LOG2E;
                coef2[j] = btl2[j] + btl2[j];
                base[j] = -btl2[j] * cs[j];
            }
            #pragma unroll
            for (int m = 0; m < 2; ++m) {
                const int r = m * 16 + lr;
                const float xsv = m ? xs1 : xs0;
                f32x4 rv;
                #pragma unroll
                for (int j = 0; j < 4; ++j) {
                    const float c0 = __builtin_fmaf(-btl2[j], xsv, base[j]);
                    rv[j] = __builtin_exp2f(__builtin_fmaf(coef2[j], acc[m][n][j], c0));
                }
                *reinterpret_cast<f32x4*>(reinterpret_cast<char*>(ob)
                    + r * 1024 + ((unsigned)(cl * 4) ^ ((unsigned)(r & 7) << 4))) = rv;
            }
        }
        __syncthreads();

        // ---- Single-segment contiguous 1KB wave stores: wave w -> rows 4w..4w+3 ----
        #pragma unroll
        for (int i = 0; i < 4; ++i) {
            const int r = w * 4 + i;
            const f32x4 v = *reinterpret_cast<const f32x4*>(reinterpret_cast<const char*>(ob)
                    + r * 1024 + ((unsigned)(l * 16) ^ ((unsigned)(r & 7) << 4)));
            *reinterpret_cast<f32x4*>(out + (size_t)(row0 + r) * K_CTR + colq + l * 4) = v;
        }
    }
}

extern "C" void kernel_launch(void* const* d_in, const int* in_sizes, int n_in,
                              void* d_out, int out_size, void* d_ws, size_t ws_size,
                              hipStream_t stream) {
    const float* x       = (const float*)d_in[0];
    const float* centers = (const float*)d_in[1];
    const float* betas   = (const float*)d_in[2];
    float* out = (float*)d_out;

    unsigned char* cbf = (unsigned char*)d_ws;                          // 256 KB fp8 fragment-major centers
    float* csq = (float*)((char*)d_ws + 262144);                        // 4 KB c_sq
    unsigned* counter = (unsigned*)((char*)d_ws + 262144 + 4096);       // 4 B arrive counter

    // Counter must be 0 at kernel start on EVERY replay (ws is not re-poisoned).
    hipMemsetAsync(counter, 0, sizeof(unsigned), stream);
    rbf_fused<<<NBLK, 512, 0, stream>>>(x, centers, cbf, csq, betas, out, counter);
}

// Round 11
// 27.259 us; speedup vs baseline: 1.8565x; 1.8565x over previous
//
#include <hip/hip_runtime.h>
#include <stdint.h>

#define D_DIM 256
#define K_CTR 1024
#define B_ROWS 16384
#define BM 32

typedef float f32x4 __attribute__((ext_vector_type(4)));
typedef float f32x2 __attribute__((ext_vector_type(2)));
typedef long long i64x2 __attribute__((ext_vector_type(2)));

// Pack 4 f32 -> 4 fp8 e4m3 bytes (OCP, HW cvt).
static __device__ __forceinline__ unsigned cvt4_fp8(const float4 v) {
    int r = __builtin_amdgcn_cvt_pk_fp8_f32(v.x, v.y, 0, false);   // bytes 0-1
    r = __builtin_amdgcn_cvt_pk_fp8_f32(v.z, v.w, r, true);        // bytes 2-3
    return (unsigned)r;
}

// Prep: centers f32 -> fp8 fragment-major (pair-interleaved) + c_sq f32.
// Value c[col][d] (kk=d>>5, p=kk>>1, e=kk&1, hk=(d>>3)&3, j=d&7) at byte:
//   (col>>4)*4096 + p*1024 + (hk*16 + (col&15))*16 + e*8 + j
// -> main's wave load (lane l) at p*1024 + l*16 is one 1KB dwordx4 holding
//    frags kk=2p (bytes 0-7) and kk=2p+1 (bytes 8-15).
__global__ __launch_bounds__(256) void rbf_prep(const float* __restrict__ centers,
                                                unsigned char* __restrict__ cbf,
                                                float* __restrict__ csq) {
    const int w = threadIdx.x >> 6;
    const int l = threadIdx.x & 63;
    const int c0 = blockIdx.x * 4 + w;
    const float4 v = *reinterpret_cast<const float4*>(centers + c0 * D_DIM + l * 4);
    float s = v.x * v.x + v.y * v.y + v.z * v.z + v.w * v.w;
    const unsigned u = cvt4_fp8(v);
    const unsigned off = (unsigned)((c0 >> 4) * 4096 + (l >> 4) * 1024
                       + (((l >> 1) & 3) * 16 + (c0 & 15)) * 16
                       + ((l >> 3) & 1) * 8 + (l & 1) * 4);
    *reinterpret_cast<unsigned*>(cbf + off) = u;
    #pragma unroll
    for (int off2 = 1; off2 < 64; off2 <<= 1) s += __shfl_xor(s, off2);
    if (l == 0) csq[c0] = s;
}

// Main: 512 thr (8 waves), block = 32 rows x 1024 cols, EIGHT phases of 128
// cols. Per phase: prefetch B(p+1), 16 MFMA, exp epilogue -> obuf[p&1] (16KB,
// swizzled), 1 barrier, then single-segment 512B wave stores. Store(p)
// overlaps MFMA/epilogue(p+1) via obuf double-buffer. LDS 40.6KB.
__global__ __launch_bounds__(512, 4) void rbf_main(const float* __restrict__ x,
                                                   const unsigned char* __restrict__ cbf,
                                                   const float* __restrict__ csq,
                                                   const float* __restrict__ betas,
                                                   float* __restrict__ out) {
    __shared__ __align__(16) unsigned char As[BM * D_DIM];   // 8 KB fp8, swizzled
    __shared__ __align__(16) float obuf[2][BM * 128];        // 2 x 16 KB, swizzled
    __shared__ float xs_lds[BM];

    const int tid = threadIdx.x;
    const int w = tid >> 6;
    const int l = tid & 63;
    // XCD-chunked bijective swizzle (512 = 8*64)
    const int strip = (blockIdx.x & 7) * 64 + (blockIdx.x >> 3);
    const int row0 = strip * BM;

    // ---- Stage A strip as fp8 (swizzled) + x_sq ----
    #pragma unroll
    for (int i = 0; i < 4; ++i) {
        const int r = i * 8 + w;
        const float4 v = *reinterpret_cast<const float4*>(x + (size_t)(row0 + r) * D_DIM + l * 4);
        float s = v.x * v.x + v.y * v.y + v.z * v.z + v.w * v.w;
        const unsigned u = cvt4_fp8(v);
        const unsigned pos = (unsigned)((l >> 4) * 64 + ((l >> 1) & 3) * 16
                           + ((l >> 3) & 1) * 8 + (l & 1) * 4);
        *reinterpret_cast<unsigned*>(As + r * 256 + (pos ^ ((unsigned)(r & 7) << 4))) = u;
        #pragma unroll
        for (int off = 1; off < 64; off <<= 1) s += __shfl_xor(s, off);
        if (l == 0) xs_lds[r] = s;
    }

    const int hk = l >> 4;
    const int lr = l & 15;
    const unsigned char* bwave = cbf + l * 16;

    // ---- Issue B(phase 0) BEFORE the barrier: wave w -> colgroup w ----
    i64x2 b0[4], b1[4];
    {
        const unsigned char* bbase = bwave + w * 4096;
        #pragma unroll
        for (int p = 0; p < 4; ++p)
            b0[p] = *reinterpret_cast<const i64x2*>(bbase + p * 1024);
    }
    __syncthreads();

    // ---- Hoist A frags once: 8 ds_read_b128 ----
    i64x2 a[2][4];
    #pragma unroll
    for (int m = 0; m < 2; ++m) {
        const int r = m * 16 + lr;
        #pragma unroll
        for (int p = 0; p < 4; ++p)
            a[m][p] = *reinterpret_cast<const i64x2*>(
                As + r * 256 + ((unsigned)(p * 64 + hk * 16) ^ ((unsigned)(lr & 7) << 4)));
    }
    const float xs0 = xs_lds[lr];
    const float xs1 = xs_lds[16 + lr];
    const float LOG2E = 1.4426950408889634f;

    #pragma unroll
    for (int ph = 0; ph < 8; ++ph) {
        const int colp = ph * 128;                 // phase col base
        const i64x2 (&bc)[4] = (ph & 1) ? b1 : b0;
        i64x2 (&bn)[4] = (ph & 1) ? b0 : b1;

        // ---- Prefetch B(ph+1): colgroup (ph+1)*8 + w ----
        if (ph < 7) {
            const unsigned char* bbase = bwave + ((ph + 1) * 8 + w) * 4096;
            #pragma unroll
            for (int p = 0; p < 4; ++p)
                bn[p] = *reinterpret_cast<const i64x2*>(bbase + p * 1024);
        }

        // ---- 16 MFMAs, 2 independent acc chains ----
        f32x4 acc[2] = {};
        #pragma unroll
        for (int p = 0; p < 4; ++p)
            #pragma unroll
            for (int m = 0; m < 2; ++m) {
                acc[m] = __builtin_amdgcn_mfma_f32_16x16x32_fp8_fp8(bc[p][0], a[m][p][0], acc[m], 0, 0, 0);
                acc[m] = __builtin_amdgcn_mfma_f32_16x16x32_fp8_fp8(bc[p][1], a[m][p][1], acc[m], 0, 0, 0);
            }

        // ---- Epilogue: exp2(fma(2*bt*log2e, acc, -bt*log2e*(xs+cs))) -> obuf ----
        float* ob = obuf[ph & 1];
        {
            const int cl = w * 16 + hk * 4;        // col within phase
            const f32x4 cs = *reinterpret_cast<const f32x4*>(csq + colp + cl);
            const f32x4 bt = *reinterpret_cast<const f32x4*>(betas + colp + cl);
            f32x4 btl2, coef2, base;
            #pragma unroll
            for (int j = 0; j < 4; ++j) {
                btl2[j] = bt[j] * LOG2E;
                coef2[j] = btl2[j] + btl2[j];
                base[j] = -btl2[j] * cs[j];
            }
            #pragma unroll
            for (int m = 0; m < 2; ++m) {
                const int r = m * 16 + lr;
                const float xsv = m ? xs1 : xs0;
                f32x4 rv;
                #pragma unroll
                for (int j = 0; j < 4; ++j) {
                    const float c0 = __builtin_fmaf(-btl2[j], xsv, base[j]);
                    rv[j] = __builtin_exp2f(__builtin_fmaf(coef2[j], acc[m][j], c0));
                }
                *reinterpret_cast<f32x4*>(reinterpret_cast<char*>(ob)
                    + r * 512 + ((unsigned)(cl * 4) ^ ((unsigned)(r & 7) << 4))) = rv;
            }
        }
        __syncthreads();

        // ---- Stores: wave w -> rows 4w..4w+3; each instr = ONE 512B segment ----
        #pragma unroll
        for (int i = 0; i < 4; ++i) {
            const int r = w * 4 + i;
            const f32x2 v = *reinterpret_cast<const f32x2*>(reinterpret_cast<const char*>(obuf[ph & 1])
                    + r * 512 + ((unsigned)(l * 8) ^ ((unsigned)(r & 7) << 4)));
            *reinterpret_cast<f32x2*>(out + (size_t)(row0 + r) * K_CTR + colp + l * 2) = v;
        }
        // No second barrier: next phase writes obuf[(ph+1)&1] (other buffer);
        // obuf[ph&1] is only rewritten at ph+2, after the ph+1 barrier.
    }
}

extern "C" void kernel_launch(void* const* d_in, const int* in_sizes, int n_in,
                              void* d_out, int out_size, void* d_ws, size_t ws_size,
                              hipStream_t stream) {
    const float* x       = (const float*)d_in[0];
    const float* centers = (const float*)d_in[1];
    const float* betas   = (const float*)d_in[2];
    float* out = (float*)d_out;

    unsigned char* cbf = (unsigned char*)d_ws;                        // 256 KB fp8 fragment-major centers
    float* csq = (float*)((char*)d_ws + (size_t)K_CTR * D_DIM);       // 4 KB c_sq

    rbf_prep<<<K_CTR / 4, 256, 0, stream>>>(centers, cbf, csq);
    rbf_main<<<B_ROWS / BM, 512, 0, stream>>>(x, cbf, csq, betas, out);
}